// Round 8
// baseline (506.530 us; speedup 1.0000x reference)
//
#include <hip/hip_runtime.h>
#include <stdint.h>

#define N_SRCN 50000
#define N_DSTN 50000
#define NE     800000
#define HIDN   256
#define NEG    0.2f

typedef __attribute__((ext_vector_type(8)))  short short8;
typedef __attribute__((ext_vector_type(16))) float float16v;

__device__ __forceinline__ float bf2f(unsigned short u){
    union { unsigned u32; float f; } c; c.u32 = ((unsigned)u) << 16; return c.f;
}
__device__ __forceinline__ unsigned short f2bf(float f){
    union { float f; unsigned u; } c; c.f = f;
    unsigned r = c.u + 0x7fffu + ((c.u >> 16) & 1u);
    return (unsigned short)(r >> 16);
}
__device__ __forceinline__ float4 ld4b(const unsigned short* p){
    uint2 u = *reinterpret_cast<const uint2*>(p);
    float4 r;
    r.x = bf2f((unsigned short)(u.x & 0xffff));
    r.y = bf2f((unsigned short)(u.x >> 16));
    r.z = bf2f((unsigned short)(u.y & 0xffff));
    r.w = bf2f((unsigned short)(u.y >> 16));
    return r;
}
// async 16B global -> LDS (wave-uniform LDS base + lane*16 dest; PER-LANE src)
__device__ __forceinline__ void gload_lds16(const unsigned short* g, unsigned short* l){
    __builtin_amdgcn_global_load_lds(
        (const __attribute__((address_space(1))) void*)g,
        (__attribute__((address_space(3))) void*)l,
        16, 0, 0);
}

// ---- pack weights, input-indexed (coalesced reads, scattered 2B writes) ----
// Wt2: [which(3)][cb(8)][kk(4)][lane(64)][8]   (49152)
// Wf : [cb(8)][kk(32)][gate(3)][lane(64)][8]   (393216), K=512 = [Wih|Whh]
//      gates adjacent per (cb,kk): one base addr + imm offsets 0/1024/2048 B
__global__ void pack_kernel(const float* __restrict__ Wsrc, const float* __restrict__ Wdst,
                            const float* __restrict__ Wres, const float* __restrict__ Wih,
                            const float* __restrict__ Whh,
                            unsigned short* __restrict__ Wt2,
                            unsigned short* __restrict__ Wf){
    int i = blockIdx.x * 256 + threadIdx.x;
    if (i < 49152){
        int which = i >> 14, j = i & 16383;          // j = k*256 + c
        int k = j >> 8, c = j & 255;
        const float* W = (which == 0) ? Wsrc : (which == 1 ? Wdst : Wres);
        float v = W[j];
        int off = which * 16384 + (c >> 5) * 2048 + (k >> 4) * 512
                + (((k >> 3) & 1) * 32 + (c & 31)) * 8 + (k & 7);
        Wt2[off] = f2bf(v);
    } else if (i < 49152 + 196608){
        int o = i - 49152;                            // Wih flat: (g*256+c)*256+k
        int row = o >> 8, k = o & 255;
        int g = row >> 8, c = row & 255;
        float v = Wih[o];
        int off = (c >> 5) * 49152 + (k >> 4) * 1536 + g * 512
                + (((k >> 3) & 1) * 32 + (c & 31)) * 8 + (k & 7);
        Wf[off] = f2bf(v);
    } else if (i < 49152 + 393216){
        int o = i - 49152 - 196608;                   // Whh
        int row = o >> 8, k = o & 255;
        int g = row >> 8, c = row & 255;
        float v = Whh[o];
        int off = (c >> 5) * 49152 + (16 + (k >> 4)) * 1536 + g * 512
                + (((k >> 3) & 1) * 32 + (c & 31)) * 8 + (k & 7);
        Wf[off] = f2bf(v);
    }
}

// ---- fused projection GEMM (K=64), z selects {src, dst, res} --------------
__global__ __launch_bounds__(256) void proj_kernel(
        const float* __restrict__ Agt, const float* __restrict__ Aag,
        const unsigned short* __restrict__ Wt2,
        const float* __restrict__ bsrc, const float* __restrict__ bdst,
        const float* __restrict__ bres,
        unsigned short* __restrict__ fs, unsigned short* __restrict__ fd,
        unsigned short* __restrict__ resb){
    __shared__ unsigned short As[64 * 72];
    __shared__ unsigned short Cs[64 * 72];
    int z = blockIdx.z;
    const float* A = (z == 0) ? Agt : Aag;
    const float* bias = (z == 0) ? bsrc : (z == 1 ? bdst : bres);
    unsigned short* out = (z == 0) ? fs : (z == 1 ? fd : resb);
    const unsigned short* Wb = Wt2 + z * 16384;
    int tid = threadIdx.x;
    int m0 = blockIdx.y * 64;
    #pragma unroll
    for (int i = 0; i < 4; ++i){
        int ci = tid + i * 256;
        int row = ci >> 4;
        int k4 = (ci & 15) << 2;
        int gr = m0 + row; if (gr >= N_SRCN) gr = N_SRCN - 1;
        float4 v = *reinterpret_cast<const float4*>(A + (size_t)gr * 64 + k4);
        unsigned short* dp = As + row * 72 + k4;
        dp[0] = f2bf(v.x); dp[1] = f2bf(v.y); dp[2] = f2bf(v.z); dp[3] = f2bf(v.w);
    }
    __syncthreads();
    int lane = tid & 63, w = tid >> 6;
    int l31 = lane & 31, half = lane >> 5;
    int msub = (w & 1) * 32;
    int cbw = blockIdx.x * 2 + (w >> 1);
    const unsigned short* bb = Wb + cbw * 2048 + lane * 8;
    const unsigned short* ap = As + (msub + l31) * 72 + half * 8;
    float16v acc = {0,0,0,0,0,0,0,0,0,0,0,0,0,0,0,0};
    #pragma unroll
    for (int ks = 0; ks < 4; ++ks){
        short8 a = *reinterpret_cast<const short8*>(ap + ks * 16);
        short8 b = *reinterpret_cast<const short8*>(bb + ks * 512);
        acc = __builtin_amdgcn_mfma_f32_32x32x16_bf16(a, b, acc, 0, 0, 0);
    }
    float bv = bias[cbw * 32 + l31];
    int ccol = (w >> 1) * 32 + l31;
    #pragma unroll
    for (int r = 0; r < 16; ++r){
        int row = (r & 3) + 8 * (r >> 2) + 4 * half + msub;
        Cs[row * 72 + ccol] = f2bf(acc[r] + bv);
    }
    __syncthreads();
    int srow = tid >> 2, chunk = tid & 3;
    int gr2 = m0 + srow;
    if (gr2 < N_SRCN){
        const uint4* sp = reinterpret_cast<const uint4*>(Cs + srow * 72 + chunk * 16);
        uint4* gp = reinterpret_cast<uint4*>(out + (size_t)gr2 * 256 + blockIdx.x * 64 + chunk * 16);
        gp[0] = sp[0];
        gp[1] = sp[1];
    }
}

// ---- edge CSR build -------------------------------------------------------
__global__ void degree_kernel(const int* __restrict__ dst, int* __restrict__ deg){
    int i = blockIdx.x * 256 + threadIdx.x;
    if (i < NE) atomicAdd(&deg[dst[i]], 1);
}

__global__ void scan1_kernel(const int* __restrict__ deg, int* __restrict__ bsum){
    __shared__ int s[256];
    int tid = threadIdx.x;
    int i = blockIdx.x * 256 + tid;
    s[tid] = (i < N_DSTN) ? deg[i] : 0;
    __syncthreads();
    #pragma unroll
    for (int off = 128; off; off >>= 1){
        if (tid < off) s[tid] += s[tid + off];
        __syncthreads();
    }
    if (tid == 0) bsum[blockIdx.x] = s[0];
}

__global__ void scan2_kernel(const int* __restrict__ bsum, int* __restrict__ boff){
    __shared__ int s[256];
    int tid = threadIdx.x;
    int v = (tid < 196) ? bsum[tid] : 0;
    s[tid] = v;
    __syncthreads();
    #pragma unroll
    for (int off = 1; off < 256; off <<= 1){
        int t = (tid >= off) ? s[tid - off] : 0;
        __syncthreads();
        s[tid] += t;
        __syncthreads();
    }
    if (tid < 196) boff[tid] = s[tid] - v;
}

__global__ void scan3_kernel(const int* __restrict__ deg, const int* __restrict__ boff,
                             int* __restrict__ ptr, int* __restrict__ cursor){
    __shared__ int s[256];
    int tid = threadIdx.x;
    int i = blockIdx.x * 256 + tid;
    int v = (i < N_DSTN) ? deg[i] : 0;
    s[tid] = v;
    __syncthreads();
    #pragma unroll
    for (int off = 1; off < 256; off <<= 1){
        int t = (tid >= off) ? s[tid - off] : 0;
        __syncthreads();
        s[tid] += t;
        __syncthreads();
    }
    int ex = s[tid] - v + boff[blockIdx.x];
    if (i < N_DSTN){ ptr[i] = ex; cursor[i] = ex; }
}

__global__ void scatter_kernel(const int* __restrict__ src, const int* __restrict__ dst,
                               int* __restrict__ cursor, int* __restrict__ csr){
    int i = blockIdx.x * 256 + threadIdx.x;
    if (i < NE){
        int d = dst[i];
        int pos = atomicAdd(&cursor[d], 1);
        csr[pos] = src[i];
    }
}

// ---- per-dst aggregation, no online max (exp safe here), 4-deep pipeline --
__global__ __launch_bounds__(256) void aggregate_kernel(
        const unsigned short* __restrict__ fs, const unsigned short* __restrict__ fd,
        const unsigned short* __restrict__ res, const float* __restrict__ attn,
        const int* __restrict__ ptr, const int* __restrict__ deg,
        const int* __restrict__ csr, unsigned short* __restrict__ x){
    int wv = threadIdx.x >> 6;
    int d = blockIdx.x * 4 + wv;
    if (d >= N_DSTN) return;
    int lane = threadIdx.x & 63;
    int c4 = lane * 4;
    float4 fdv = ld4b(fd + (size_t)d * 256 + c4);
    float4 at = *reinterpret_cast<const float4*>(attn + (lane >> 4) * 64 + (lane & 15) * 4);
    int p = ptr[d], dg = deg[d];
    float l = 0.f;
    float4 acc = make_float4(0.f, 0.f, 0.f, 0.f);
    for (int base = 0; base < dg; base += 64){
        int cnt = min(64, dg - base);
        int sreg = (lane < cnt) ? csr[p + base + lane] : 0;
        float4 b0 = ld4b(fs + (size_t)__shfl(sreg, 0) * 256 + c4);
        float4 b1 = ld4b(fs + (size_t)__shfl(sreg, 1 & 63) * 256 + c4);
        float4 b2 = ld4b(fs + (size_t)__shfl(sreg, 2 & 63) * 256 + c4);
        float4 b3 = ld4b(fs + (size_t)__shfl(sreg, 3 & 63) * 256 + c4);
        for (int j = 0; j < cnt; j += 4){
            float4 n0 = ld4b(fs + (size_t)__shfl(sreg, (j + 4) & 63) * 256 + c4);
            float4 n1 = ld4b(fs + (size_t)__shfl(sreg, (j + 5) & 63) * 256 + c4);
            float4 n2 = ld4b(fs + (size_t)__shfl(sreg, (j + 6) & 63) * 256 + c4);
            float4 n3 = ld4b(fs + (size_t)__shfl(sreg, (j + 7) & 63) * 256 + c4);
#define PROC(BV, T) { \
            float ex = BV.x + fdv.x; ex = ex > 0.f ? ex : NEG * ex; \
            float ey = BV.y + fdv.y; ey = ey > 0.f ? ey : NEG * ey; \
            float ez = BV.z + fdv.z; ez = ez > 0.f ? ez : NEG * ez; \
            float ew = BV.w + fdv.w; ew = ew > 0.f ? ew : NEG * ew; \
            float part = ex * at.x + ey * at.y + ez * at.z + ew * at.w; \
            part += __shfl_xor(part, 1); \
            part += __shfl_xor(part, 2); \
            part += __shfl_xor(part, 4); \
            part += __shfl_xor(part, 8); \
            float wgt = ((j + (T)) < cnt) ? __expf(part) : 0.f; \
            l += wgt; \
            acc.x = fmaf(wgt, BV.x, acc.x); \
            acc.y = fmaf(wgt, BV.y, acc.y); \
            acc.z = fmaf(wgt, BV.z, acc.z); \
            acc.w = fmaf(wgt, BV.w, acc.w); }
            PROC(b0, 0) PROC(b1, 1) PROC(b2, 2) PROC(b3, 3)
#undef PROC
            b0 = n0; b1 = n1; b2 = n2; b3 = n3;
        }
    }
    float inv = (l > 0.f) ? 1.f / l : 0.f;
    float4 rv = ld4b(res + (size_t)d * 256 + c4);
    float xx = fmaxf(fmaf(acc.x, inv, rv.x), 0.f);
    float xy = fmaxf(fmaf(acc.y, inv, rv.y), 0.f);
    float xz = fmaxf(fmaf(acc.z, inv, rv.z), 0.f);
    float xw = fmaxf(fmaf(acc.w, inv, rv.w), 0.f);
    uint2 o;
    o.x = (unsigned)f2bf(xx) | ((unsigned)f2bf(xy) << 16);
    o.y = (unsigned)f2bf(xz) | ((unsigned)f2bf(xw) << 16);
    *reinterpret_cast<uint2*>(x + (size_t)d * 256 + c4) = o;
}

// ---- GRU v12: register-level B reuse -- each B fragment feeds 2 MFMAs -----
// v6-v11 post-mortem: all variants pinned at 116-157us because every B
// fragment was loaded for exactly ONE MFMA -> 1.2GB of B-operand traffic
// through L2 (4.7MB/CU), the true invariant wall. MfmaUtil*dur == MFMA floor
// in every run: the pipe is fine, the B-stream is the cost. v12: 2 row-tiles
// per wave (BM=64), so each loaded B fragment feeds 2 MFMAs -> B traffic
// halves to 600MB and per-row prologue overhead halves (782 blocks).
// Register budget is the v5 lesson inverted: 8-wave block @
// __launch_bounds__(512,2) = 256 regs/wave; 8 accs (128) + B (12) + A (8)
// + addr ~30 = ~180, ~70 spare for the compiler's load pipelining.
// Keeps v11's barrier-free K-loop (A-only LDS, B gate-adjacent direct loads).
__global__ __launch_bounds__(512, 2) void gru_kernel(
        const unsigned short* __restrict__ Xb,
        const float* __restrict__ H0, const unsigned short* __restrict__ Wf,
        const float* __restrict__ bih, const float* __restrict__ bhh,
        float* __restrict__ outH){
    __shared__ unsigned short As[2 * 64 * 256];  // 64KB: [X 64x256][H 64x256]
    int tid = threadIdx.x;
    int m0 = blockIdx.x << 6;                    // 64 rows/block
    int w = tid >> 6, lane = tid & 63;

    // ---- prologue A: X region via async gload (swizzled SOURCE, linear dest)
    #pragma unroll
    for (int i = 0; i < 4; ++i){
        int g = w * 4 + i;                       // 0..31, rows {2g, 2g+1}
        int row = 2 * g + (lane >> 5);
        int gr = m0 + row; if (gr >= N_DSTN) gr = N_DSTN - 1;
        int j = lane & 31;
        const unsigned short* src = Xb + (size_t)gr * 256 + ((j ^ (row & 15)) << 3);
        gload_lds16(src, As + g * 512);
    }
    // ---- prologue A: H region reg-staged f32->bf16 (once per element)
    #pragma unroll
    for (int s = 0; s < 2; ++s){
        int hrow = tid >> 3;                     // 64 rows, 8 threads/row
        int hseg = (tid & 7) * 2 + s;            // 16 segs of 16 f32
        int hgr = m0 + hrow; if (hgr >= N_DSTN) hgr = N_DSTN - 1;
        const float* hp = H0 + (size_t)hgr * 256 + hseg * 16;
        float4 f0 = *reinterpret_cast<const float4*>(hp);
        float4 f1 = *reinterpret_cast<const float4*>(hp + 4);
        float4 f2 = *reinterpret_cast<const float4*>(hp + 8);
        float4 f3 = *reinterpret_cast<const float4*>(hp + 12);
        int rl = hrow & 15;
        int c0 = hseg * 2;
        uint4 o;
        o.x = (unsigned)f2bf(f0.x) | ((unsigned)f2bf(f0.y) << 16);
        o.y = (unsigned)f2bf(f0.z) | ((unsigned)f2bf(f0.w) << 16);
        o.z = (unsigned)f2bf(f1.x) | ((unsigned)f2bf(f1.y) << 16);
        o.w = (unsigned)f2bf(f1.z) | ((unsigned)f2bf(f1.w) << 16);
        *reinterpret_cast<uint4*>(As + 16384 + hrow * 256 + ((c0 ^ rl) << 3)) = o;
        o.x = (unsigned)f2bf(f2.x) | ((unsigned)f2bf(f2.y) << 16);
        o.y = (unsigned)f2bf(f2.z) | ((unsigned)f2bf(f2.w) << 16);
        o.z = (unsigned)f2bf(f3.x) | ((unsigned)f2bf(f3.y) << 16);
        o.w = (unsigned)f2bf(f3.z) | ((unsigned)f2bf(f3.w) << 16);
        *reinterpret_cast<uint4*>(As + 16384 + hrow * 256 + (((c0 + 1) ^ rl) << 3)) = o;
    }
    asm volatile("s_waitcnt vmcnt(0) lgkmcnt(0)" ::: "memory");
    __syncthreads();                             // the ONLY barrier

    int l31 = lane & 31, half = lane >> 5;
    int ct = w;                                  // 8 col-tiles of 32
    int rl = l31 & 15;                           // same for row and row+32
    const unsigned short* bb = Wf + ct * 49152 + lane * 8;   // gate-adjacent
    float16v zv = {0,0,0,0,0,0,0,0,0,0,0,0,0,0,0,0};
    float16v ar0 = zv, az0 = zv, anx0 = zv, anh0 = zv;
    float16v ar1 = zv, az1 = zv, anx1 = zv, anh1 = zv;
    #pragma unroll
    for (int p = 0; p < 32; ++p){
        const unsigned short* bp = bb + p * 1536;
        short8 vr = *reinterpret_cast<const short8*>(bp);          // off 0
        short8 vz = *reinterpret_cast<const short8*>(bp + 512);    // off 1024B
        short8 vn = *reinterpret_cast<const short8*>(bp + 1024);   // off 2048B
        const unsigned short* ap_ = (p < 16) ? As : (As + 16384);
        int kl = p & 15;
        int ko = ((kl * 2 + half) ^ rl) << 3;
        short8 a0 = *reinterpret_cast<const short8*>(ap_ + l31 * 256 + ko);
        short8 a1 = *reinterpret_cast<const short8*>(ap_ + (32 + l31) * 256 + ko);
        ar0 = __builtin_amdgcn_mfma_f32_32x32x16_bf16(a0, vr, ar0, 0, 0, 0);
        ar1 = __builtin_amdgcn_mfma_f32_32x32x16_bf16(a1, vr, ar1, 0, 0, 0);
        az0 = __builtin_amdgcn_mfma_f32_32x32x16_bf16(a0, vz, az0, 0, 0, 0);
        az1 = __builtin_amdgcn_mfma_f32_32x32x16_bf16(a1, vz, az1, 0, 0, 0);
        if (p < 16){
            anx0 = __builtin_amdgcn_mfma_f32_32x32x16_bf16(a0, vn, anx0, 0, 0, 0);
            anx1 = __builtin_amdgcn_mfma_f32_32x32x16_bf16(a1, vn, anx1, 0, 0, 0);
        } else {
            anh0 = __builtin_amdgcn_mfma_f32_32x32x16_bf16(a0, vn, anh0, 0, 0, 0);
            anh1 = __builtin_amdgcn_mfma_f32_32x32x16_bf16(a1, vn, anh1, 0, 0, 0);
        }
    }
    // fused GRU epilogue; H0 rows are L2-hot (read in prologue by this block)
    int cg = ct * 32 + l31;
    float rb = bih[cg] + bhh[cg];
    float zb = bih[256 + cg] + bhh[256 + cg];
    float bin = bih[512 + cg], bhn = bhh[512 + cg];
#define EPI(AR, AZ, ANX, ANH, T) { \
    _Pragma("unroll") \
    for (int r = 0; r < 16; ++r){ \
        int m = m0 + (T) * 32 + (r & 3) + 8 * (r >> 2) + 4 * half; \
        if (m < N_DSTN){ \
            float h0v = H0[(size_t)m * 256 + cg]; \
            float rrg = 1.f / (1.f + __expf(-((AR)[r] + rb))); \
            float zg  = 1.f / (1.f + __expf(-((AZ)[r] + zb))); \
            float nx = (ANX)[r] + bin + rrg * ((ANH)[r] + bhn); \
            float tm = __expf(-2.f * fabsf(nx)); \
            float nn = (1.f - tm) / (1.f + tm); \
            nn = (nx >= 0.f) ? nn : -nn; \
            outH[(size_t)m * 256 + cg] = (1.f - zg) * nn + zg * h0v; \
        } \
    } }
    EPI(ar0, az0, anx0, anh0, 0)
    EPI(ar1, az1, anx1, anh1, 1)
#undef EPI
}

// ---- logits = h @ W_out + b_out ------------------------------------------
__global__ __launch_bounds__(256) void logits_kernel(
        const float* __restrict__ H, const float* __restrict__ Wout,
        const float* __restrict__ bout, float* __restrict__ outL){
    __shared__ float Hl[16 * 260];
    __shared__ float Wl[16 * 260];
    int tid = threadIdx.x;
    int m0 = blockIdx.x * 16;
    #pragma unroll
    for (int i = 0; i < 4; ++i){
        int ci = tid + i * 256;
        int row = ci >> 6;
        int c4 = (ci & 63) << 2;
        int gr = m0 + row; if (gr >= N_DSTN) gr = N_DSTN - 1;
        float4 v = *reinterpret_cast<const float4*>(H + (size_t)gr * 256 + c4);
        float* dp = Hl + row * 260 + c4;
        dp[0] = v.x; dp[1] = v.y; dp[2] = v.z; dp[3] = v.w;
    }
    #pragma unroll
    for (int i = 0; i < 16; ++i){
        int ci = tid + i * 256;
        int c = ci >> 4, j = ci & 15;
        Wl[j * 260 + c] = Wout[c * 16 + j];
    }
    __syncthreads();
    int row = tid >> 4, j = tid & 15;
    const float* hr = Hl + row * 260;
    const float* wr = Wl + j * 260;
    float acc = bout[j];
    #pragma unroll
    for (int c = 0; c < 256; c += 4){
        float4 hv = *reinterpret_cast<const float4*>(hr + c);
        float4 wv = *reinterpret_cast<const float4*>(wr + c);
        acc = fmaf(hv.x, wv.x, fmaf(hv.y, wv.y, fmaf(hv.z, wv.z, fmaf(hv.w, wv.w, acc))));
    }
    int m = m0 + row;
    if (m < N_DSTN) outL[m * 16 + j] = acc;
}

extern "C" void kernel_launch(void* const* d_in, const int* in_sizes, int n_in,
                              void* d_out, int out_size, void* d_ws, size_t ws_size,
                              hipStream_t stream){
    const float* feat_gt = (const float*)d_in[0];
    const float* feat_ag = (const float*)d_in[1];
    const float* h0      = (const float*)d_in[2];
    const int*   e_src   = (const int*)d_in[3];
    const int*   e_dst   = (const int*)d_in[4];
    const float* W_src   = (const float*)d_in[5];
    const float* b_src   = (const float*)d_in[6];
    const float* W_dst   = (const float*)d_in[7];
    const float* b_dst   = (const float*)d_in[8];
    const float* attn    = (const float*)d_in[9];
    const float* W_res   = (const float*)d_in[10];
    const float* b_res   = (const float*)d_in[11];
    const float* W_ih    = (const float*)d_in[12];
    const float* W_hh    = (const float*)d_in[13];
    const float* b_ih    = (const float*)d_in[14];
    const float* b_hh    = (const float*)d_in[15];
    const float* W_out   = (const float*)d_in[16];
    const float* b_out   = (const float*)d_in[17];

    float* outL = (float*)d_out;
    float* outH = outL + (size_t)N_DSTN * 16;

    char* ws = (char*)d_ws;
    size_t off = 0;
    auto alloc = [&](size_t bytes) -> void* {
        void* p = ws + off; off = (off + bytes + 255) & ~(size_t)255; return p;
    };
    unsigned short* fs   = (unsigned short*)alloc((size_t)N_SRCN * 256 * 2);
    unsigned short* fd   = (unsigned short*)alloc((size_t)N_DSTN * 256 * 2);
    unsigned short* res  = (unsigned short*)alloc((size_t)N_DSTN * 256 * 2);
    unsigned short* xb   = (unsigned short*)alloc((size_t)N_DSTN * 256 * 2);
    unsigned short* Wt2  = (unsigned short*)alloc(49152 * 2);
    unsigned short* Wf   = (unsigned short*)alloc(393216 * 2);
    int* deg    = (int*)alloc(N_DSTN * 4);
    int* ptr    = (int*)alloc(N_DSTN * 4);
    int* cursor = (int*)alloc(N_DSTN * 4);
    int* csr    = (int*)alloc((size_t)NE * 4);
    int* bsum   = (int*)alloc(256 * 4);
    int* boff   = (int*)alloc(256 * 4);

    hipMemsetAsync(deg, 0, N_DSTN * 4, stream);
    pack_kernel<<<1728, 256, 0, stream>>>(W_src, W_dst, W_res, W_ih, W_hh, Wt2, Wf);

    proj_kernel<<<dim3(4, 782, 3), 256, 0, stream>>>(feat_gt, feat_ag, Wt2,
                                                     b_src, b_dst, b_res, fs, fd, res);

    degree_kernel<<<3125, 256, 0, stream>>>(e_dst, deg);
    scan1_kernel<<<196, 256, 0, stream>>>(deg, bsum);
    scan2_kernel<<<1, 256, 0, stream>>>(bsum, boff);
    scan3_kernel<<<196, 256, 0, stream>>>(deg, boff, ptr, cursor);
    scatter_kernel<<<3125, 256, 0, stream>>>(e_src, e_dst, cursor, csr);
    aggregate_kernel<<<12500, 256, 0, stream>>>(fs, fd, res, attn, ptr, deg, csr, xb);

    gru_kernel<<<782, 512, 0, stream>>>(xb, h0, Wf, b_ih, b_hh, outH);
    logits_kernel<<<3125, 256, 0, stream>>>(outH, W_out, b_out, outL);
}

// Round 9
// 445.836 us; speedup vs baseline: 1.1361x; 1.1361x over previous
//
#include <hip/hip_runtime.h>
#include <stdint.h>

#define N_SRCN 50000
#define N_DSTN 50000
#define NE     800000
#define HIDN   256
#define NEG    0.2f

typedef __attribute__((ext_vector_type(8)))  short short8;
typedef __attribute__((ext_vector_type(16))) float float16v;

__device__ __forceinline__ float bf2f(unsigned short u){
    union { unsigned u32; float f; } c; c.u32 = ((unsigned)u) << 16; return c.f;
}
__device__ __forceinline__ unsigned short f2bf(float f){
    union { float f; unsigned u; } c; c.f = f;
    unsigned r = c.u + 0x7fffu + ((c.u >> 16) & 1u);
    return (unsigned short)(r >> 16);
}
__device__ __forceinline__ float4 ld4b(const unsigned short* p){
    uint2 u = *reinterpret_cast<const uint2*>(p);
    float4 r;
    r.x = bf2f((unsigned short)(u.x & 0xffff));
    r.y = bf2f((unsigned short)(u.x >> 16));
    r.z = bf2f((unsigned short)(u.y & 0xffff));
    r.w = bf2f((unsigned short)(u.y >> 16));
    return r;
}
__device__ __forceinline__ void unpack8(uint4 u, float* f){
    f[0] = bf2f((unsigned short)(u.x & 0xffff)); f[1] = bf2f((unsigned short)(u.x >> 16));
    f[2] = bf2f((unsigned short)(u.y & 0xffff)); f[3] = bf2f((unsigned short)(u.y >> 16));
    f[4] = bf2f((unsigned short)(u.z & 0xffff)); f[5] = bf2f((unsigned short)(u.z >> 16));
    f[6] = bf2f((unsigned short)(u.w & 0xffff)); f[7] = bf2f((unsigned short)(u.w >> 16));
}
// async 16B global -> LDS (wave-uniform LDS base + lane*16 dest; PER-LANE src)
__device__ __forceinline__ void gload_lds16(const unsigned short* g, unsigned short* l){
    __builtin_amdgcn_global_load_lds(
        (const __attribute__((address_space(1))) void*)g,
        (__attribute__((address_space(3))) void*)l,
        16, 0, 0);
}

// ---- pack weights, input-indexed (coalesced reads, scattered 2B writes) ----
// Wt2: [which(3)][cb(8)][kk(4)][lane(64)][8]   (49152)
// Wf : [cb(8)][kk(32)][gate(3)][lane(64)][8]   (393216), K=512 = [Wih|Whh]
//      gates adjacent per (cb,kk): one base addr + imm offsets 0/1024/2048 B
__global__ void pack_kernel(const float* __restrict__ Wsrc, const float* __restrict__ Wdst,
                            const float* __restrict__ Wres, const float* __restrict__ Wih,
                            const float* __restrict__ Whh,
                            unsigned short* __restrict__ Wt2,
                            unsigned short* __restrict__ Wf){
    int i = blockIdx.x * 256 + threadIdx.x;
    if (i < 49152){
        int which = i >> 14, j = i & 16383;          // j = k*256 + c
        int k = j >> 8, c = j & 255;
        const float* W = (which == 0) ? Wsrc : (which == 1 ? Wdst : Wres);
        float v = W[j];
        int off = which * 16384 + (c >> 5) * 2048 + (k >> 4) * 512
                + (((k >> 3) & 1) * 32 + (c & 31)) * 8 + (k & 7);
        Wt2[off] = f2bf(v);
    } else if (i < 49152 + 196608){
        int o = i - 49152;                            // Wih flat: (g*256+c)*256+k
        int row = o >> 8, k = o & 255;
        int g = row >> 8, c = row & 255;
        float v = Wih[o];
        int off = (c >> 5) * 49152 + (k >> 4) * 1536 + g * 512
                + (((k >> 3) & 1) * 32 + (c & 31)) * 8 + (k & 7);
        Wf[off] = f2bf(v);
    } else if (i < 49152 + 393216){
        int o = i - 49152 - 196608;                   // Whh
        int row = o >> 8, k = o & 255;
        int g = row >> 8, c = row & 255;
        float v = Whh[o];
        int off = (c >> 5) * 49152 + (16 + (k >> 4)) * 1536 + g * 512
                + (((k >> 3) & 1) * 32 + (c & 31)) * 8 + (k & 7);
        Wf[off] = f2bf(v);
    }
}

// ---- fused projection GEMM (K=64), z selects {src, dst, res} --------------
__global__ __launch_bounds__(256) void proj_kernel(
        const float* __restrict__ Agt, const float* __restrict__ Aag,
        const unsigned short* __restrict__ Wt2,
        const float* __restrict__ bsrc, const float* __restrict__ bdst,
        const float* __restrict__ bres,
        unsigned short* __restrict__ fs, unsigned short* __restrict__ fd,
        unsigned short* __restrict__ resb){
    __shared__ unsigned short As[64 * 72];
    __shared__ unsigned short Cs[64 * 72];
    int z = blockIdx.z;
    const float* A = (z == 0) ? Agt : Aag;
    const float* bias = (z == 0) ? bsrc : (z == 1 ? bdst : bres);
    unsigned short* out = (z == 0) ? fs : (z == 1 ? fd : resb);
    const unsigned short* Wb = Wt2 + z * 16384;
    int tid = threadIdx.x;
    int m0 = blockIdx.y * 64;
    #pragma unroll
    for (int i = 0; i < 4; ++i){
        int ci = tid + i * 256;
        int row = ci >> 4;
        int k4 = (ci & 15) << 2;
        int gr = m0 + row; if (gr >= N_SRCN) gr = N_SRCN - 1;
        float4 v = *reinterpret_cast<const float4*>(A + (size_t)gr * 64 + k4);
        unsigned short* dp = As + row * 72 + k4;
        dp[0] = f2bf(v.x); dp[1] = f2bf(v.y); dp[2] = f2bf(v.z); dp[3] = f2bf(v.w);
    }
    __syncthreads();
    int lane = tid & 63, w = tid >> 6;
    int l31 = lane & 31, half = lane >> 5;
    int msub = (w & 1) * 32;
    int cbw = blockIdx.x * 2 + (w >> 1);
    const unsigned short* bb = Wb + cbw * 2048 + lane * 8;
    const unsigned short* ap = As + (msub + l31) * 72 + half * 8;
    float16v acc = {0,0,0,0,0,0,0,0,0,0,0,0,0,0,0,0};
    #pragma unroll
    for (int ks = 0; ks < 4; ++ks){
        short8 a = *reinterpret_cast<const short8*>(ap + ks * 16);
        short8 b = *reinterpret_cast<const short8*>(bb + ks * 512);
        acc = __builtin_amdgcn_mfma_f32_32x32x16_bf16(a, b, acc, 0, 0, 0);
    }
    float bv = bias[cbw * 32 + l31];
    int ccol = (w >> 1) * 32 + l31;
    #pragma unroll
    for (int r = 0; r < 16; ++r){
        int row = (r & 3) + 8 * (r >> 2) + 4 * half + msub;
        Cs[row * 72 + ccol] = f2bf(acc[r] + bv);
    }
    __syncthreads();
    int srow = tid >> 2, chunk = tid & 3;
    int gr2 = m0 + srow;
    if (gr2 < N_SRCN){
        const uint4* sp = reinterpret_cast<const uint4*>(Cs + srow * 72 + chunk * 16);
        uint4* gp = reinterpret_cast<uint4*>(out + (size_t)gr2 * 256 + blockIdx.x * 64 + chunk * 16);
        gp[0] = sp[0];
        gp[1] = sp[1];
    }
}

// ---- edge CSR build -------------------------------------------------------
__global__ void degree_kernel(const int* __restrict__ dst, int* __restrict__ deg){
    int i = blockIdx.x * 256 + threadIdx.x;
    if (i < NE) atomicAdd(&deg[dst[i]], 1);
}

__global__ void scan1_kernel(const int* __restrict__ deg, int* __restrict__ bsum){
    __shared__ int s[256];
    int tid = threadIdx.x;
    int i = blockIdx.x * 256 + tid;
    s[tid] = (i < N_DSTN) ? deg[i] : 0;
    __syncthreads();
    #pragma unroll
    for (int off = 128; off; off >>= 1){
        if (tid < off) s[tid] += s[tid + off];
        __syncthreads();
    }
    if (tid == 0) bsum[blockIdx.x] = s[0];
}

__global__ void scan2_kernel(const int* __restrict__ bsum, int* __restrict__ boff){
    __shared__ int s[256];
    int tid = threadIdx.x;
    int v = (tid < 196) ? bsum[tid] : 0;
    s[tid] = v;
    __syncthreads();
    #pragma unroll
    for (int off = 1; off < 256; off <<= 1){
        int t = (tid >= off) ? s[tid - off] : 0;
        __syncthreads();
        s[tid] += t;
        __syncthreads();
    }
    if (tid < 196) boff[tid] = s[tid] - v;
}

__global__ void scan3_kernel(const int* __restrict__ deg, const int* __restrict__ boff,
                             int* __restrict__ ptr, int* __restrict__ cursor){
    __shared__ int s[256];
    int tid = threadIdx.x;
    int i = blockIdx.x * 256 + tid;
    int v = (i < N_DSTN) ? deg[i] : 0;
    s[tid] = v;
    __syncthreads();
    #pragma unroll
    for (int off = 1; off < 256; off <<= 1){
        int t = (tid >= off) ? s[tid - off] : 0;
        __syncthreads();
        s[tid] += t;
        __syncthreads();
    }
    int ex = s[tid] - v + boff[blockIdx.x];
    if (i < N_DSTN){ ptr[i] = ex; cursor[i] = ex; }
}

__global__ void scatter_kernel(const int* __restrict__ src, const int* __restrict__ dst,
                               int* __restrict__ cursor, int* __restrict__ csr){
    int i = blockIdx.x * 256 + threadIdx.x;
    if (i < NE){
        int d = dst[i];
        int pos = atomicAdd(&cursor[d], 1);
        csr[pos] = src[i];
    }
}

// ---- aggregate v2: 2 edges per wave-step ----------------------------------
// Previous: 1 edge/step, 8B/lane, 4-shfl reduce over 16 lanes = ~35 wave-ops
// per edge x 800k edges. v2: wave splits into two 32-lane edge slots; each
// lane covers 8 cols (16B loads). Head = 8 lanes x 8 cols -> 3-shfl reduce.
// Cross-slot combine at the end (shfl_xor 32). Per-edge wave cost ~halves.
__global__ __launch_bounds__(256) void aggregate_kernel(
        const unsigned short* __restrict__ fs, const unsigned short* __restrict__ fd,
        const unsigned short* __restrict__ res, const float* __restrict__ attn,
        const int* __restrict__ ptr, const int* __restrict__ deg,
        const int* __restrict__ csr, unsigned short* __restrict__ x){
    int wv = threadIdx.x >> 6;
    int d = blockIdx.x * 4 + wv;
    if (d >= N_DSTN) return;
    int lane = threadIdx.x & 63;
    int s = lane >> 5;                    // edge slot 0/1
    int sl = lane & 31;                   // sub-lane: cols [sl*8, sl*8+8)
    int c8 = sl * 8;
    float fdv[8];
    unpack8(*reinterpret_cast<const uint4*>(fd + (size_t)d * 256 + c8), fdv);
    // attn for this lane's 8 cols: head = sl>>3, feat = (sl&7)*8 + i
    const float* atp = attn + (sl >> 3) * 64 + (sl & 7) * 8;
    float4 at0 = *reinterpret_cast<const float4*>(atp);
    float4 at1 = *reinterpret_cast<const float4*>(atp + 4);
    float at[8] = {at0.x, at0.y, at0.z, at0.w, at1.x, at1.y, at1.z, at1.w};
    int p = ptr[d], dg = deg[d];
    float lsum = 0.f;
    float acc[8] = {0.f, 0.f, 0.f, 0.f, 0.f, 0.f, 0.f, 0.f};
    for (int base = 0; base < dg; base += 64){
        int cnt = min(64, dg - base);
        int sreg = (lane < cnt) ? csr[p + base + lane] : 0;
        uint4 cur = *reinterpret_cast<const uint4*>(
            fs + (size_t)__shfl(sreg, s) * 256 + c8);
        for (int j = 0; j < cnt; j += 2){
            uint4 nxt = *reinterpret_cast<const uint4*>(
                fs + (size_t)__shfl(sreg, (j + 2 + s) & 63) * 256 + c8);
            float b[8];
            unpack8(cur, b);
            float part = 0.f;
            #pragma unroll
            for (int i = 0; i < 8; ++i){
                float e = b[i] + fdv[i];
                e = (e > 0.f) ? e : NEG * e;
                part = fmaf(e, at[i], part);
            }
            part += __shfl_xor(part, 1);
            part += __shfl_xor(part, 2);
            part += __shfl_xor(part, 4);   // per-head score (8 lanes x 8 cols)
            float wgt = ((j + s) < cnt) ? __expf(part) : 0.f;
            lsum += wgt;
            #pragma unroll
            for (int i = 0; i < 8; ++i) acc[i] = fmaf(wgt, b[i], acc[i]);
            cur = nxt;
        }
    }
    // combine the two edge slots (partner lane has same cols, same head)
    lsum += __shfl_xor(lsum, 32);
    #pragma unroll
    for (int i = 0; i < 8; ++i) acc[i] += __shfl_xor(acc[i], 32);
    float inv = (lsum > 0.f) ? 1.f / lsum : 0.f;
    float rv[8];
    unpack8(*reinterpret_cast<const uint4*>(res + (size_t)d * 256 + c8), rv);
    unsigned short ob[8];
    #pragma unroll
    for (int i = 0; i < 8; ++i)
        ob[i] = f2bf(fmaxf(fmaf(acc[i], inv, rv[i]), 0.f));
    if (s == 0){
        uint4 o;
        o.x = (unsigned)ob[0] | ((unsigned)ob[1] << 16);
        o.y = (unsigned)ob[2] | ((unsigned)ob[3] << 16);
        o.z = (unsigned)ob[4] | ((unsigned)ob[5] << 16);
        o.w = (unsigned)ob[6] | ((unsigned)ob[7] << 16);
        *reinterpret_cast<uint4*>(x + (size_t)d * 256 + c8) = o;
    }
}

// ---- GRU v11 (best measured: 116us): barrier-free K-loop; B global->reg ---
// v12's 2-tile B-reuse regressed (170us): halving waves hurt more than
// halving bytes helped -> GRU is latency/TLP-bound. v11 = 16 waves/CU,
// A-only LDS (one barrier), B streamed gate-adjacent direct to VGPRs.
__global__ __launch_bounds__(512, 4) void gru_kernel(
        const unsigned short* __restrict__ Xb,
        const float* __restrict__ H0, const unsigned short* __restrict__ Wf,
        const float* __restrict__ bih, const float* __restrict__ bhh,
        float* __restrict__ outH){
    __shared__ unsigned short As[2 * 32 * 256];  // 32KB: [X 32x256][H 32x256]
    int tid = threadIdx.x;
    int m0 = blockIdx.x << 5;                    // 32 rows/block
    int w = tid >> 6, lane = tid & 63;

    // ---- prologue A: X region via async gload (swizzled SOURCE, linear dest)
    #pragma unroll
    for (int i = 0; i < 2; ++i){
        int g = w + i * 8;                       // 0..15, rows {2g, 2g+1}
        int row = 2 * g + (lane >> 5);
        int gr = m0 + row; if (gr >= N_DSTN) gr = N_DSTN - 1;
        int j = lane & 31;
        const unsigned short* src = Xb + (size_t)gr * 256 + ((j ^ (row & 15)) << 3);
        gload_lds16(src, As + g * 512);
    }
    // ---- prologue A: H region reg-staged f32->bf16 (once per element)
    {
        int hrow = tid >> 4, hseg = tid & 15;    // 32 rows x 16 segs of 16 f32
        int hgr = m0 + hrow; if (hgr >= N_DSTN) hgr = N_DSTN - 1;
        const float* hp = H0 + (size_t)hgr * 256 + hseg * 16;
        float4 f0 = *reinterpret_cast<const float4*>(hp);
        float4 f1 = *reinterpret_cast<const float4*>(hp + 4);
        float4 f2 = *reinterpret_cast<const float4*>(hp + 8);
        float4 f3 = *reinterpret_cast<const float4*>(hp + 12);
        int rl = hrow & 15;
        int c0 = hseg * 2;
        uint4 o;
        o.x = (unsigned)f2bf(f0.x) | ((unsigned)f2bf(f0.y) << 16);
        o.y = (unsigned)f2bf(f0.z) | ((unsigned)f2bf(f0.w) << 16);
        o.z = (unsigned)f2bf(f1.x) | ((unsigned)f2bf(f1.y) << 16);
        o.w = (unsigned)f2bf(f1.z) | ((unsigned)f2bf(f1.w) << 16);
        *reinterpret_cast<uint4*>(As + 8192 + hrow * 256 + ((c0 ^ rl) << 3)) = o;
        o.x = (unsigned)f2bf(f2.x) | ((unsigned)f2bf(f2.y) << 16);
        o.y = (unsigned)f2bf(f2.z) | ((unsigned)f2bf(f2.w) << 16);
        o.z = (unsigned)f2bf(f3.x) | ((unsigned)f2bf(f3.y) << 16);
        o.w = (unsigned)f2bf(f3.z) | ((unsigned)f2bf(f3.w) << 16);
        *reinterpret_cast<uint4*>(As + 8192 + hrow * 256 + (((c0 + 1) ^ rl) << 3)) = o;
    }
    asm volatile("s_waitcnt vmcnt(0) lgkmcnt(0)" ::: "memory");
    __syncthreads();                             // the ONLY barrier

    int l31 = lane & 31, half = lane >> 5;
    int ct = w;                                  // 8 col-tiles of 32
    int rl = l31 & 15;
    const unsigned short* bb = Wf + ct * 49152 + lane * 8;   // gate-adjacent
    float16v zv = {0,0,0,0,0,0,0,0,0,0,0,0,0,0,0,0};
    float16v ar = zv, az = zv, anx = zv, anh = zv;
    #pragma unroll
    for (int p = 0; p < 32; ++p){
        const unsigned short* bp = bb + p * 1536;
        short8 vr = *reinterpret_cast<const short8*>(bp);          // off 0
        short8 vz = *reinterpret_cast<const short8*>(bp + 512);    // off 1024B
        short8 vn = *reinterpret_cast<const short8*>(bp + 1024);   // off 2048B
        const unsigned short* ap_ = (p < 16) ? As : (As + 8192);
        int kl = p & 15;
        short8 a = *reinterpret_cast<const short8*>(
                       ap_ + l31 * 256 + (((kl * 2 + half) ^ rl) << 3));
        ar = __builtin_amdgcn_mfma_f32_32x32x16_bf16(a, vr, ar, 0, 0, 0);
        az = __builtin_amdgcn_mfma_f32_32x32x16_bf16(a, vz, az, 0, 0, 0);
        if (p < 16) anx = __builtin_amdgcn_mfma_f32_32x32x16_bf16(a, vn, anx, 0, 0, 0);
        else        anh = __builtin_amdgcn_mfma_f32_32x32x16_bf16(a, vn, anh, 0, 0, 0);
    }
    // fused GRU epilogue; H0 rows are L2-hot (read in prologue by this block)
    int cg = ct * 32 + l31;
    float rb = bih[cg] + bhh[cg];
    float zb = bih[256 + cg] + bhh[256 + cg];
    float bin = bih[512 + cg], bhn = bhh[512 + cg];
    #pragma unroll
    for (int r = 0; r < 16; ++r){
        int m = m0 + (r & 3) + 8 * (r >> 2) + 4 * half;
        if (m < N_DSTN){
            float h0v = H0[(size_t)m * 256 + cg];
            float rrg = 1.f / (1.f + __expf(-(ar[r] + rb)));
            float zg  = 1.f / (1.f + __expf(-(az[r] + zb)));
            float nx = anx[r] + bin + rrg * (anh[r] + bhn);
            float tm = __expf(-2.f * fabsf(nx));
            float nn = (1.f - tm) / (1.f + tm);
            nn = (nx >= 0.f) ? nn : -nn;
            outH[(size_t)m * 256 + cg] = (1.f - zg) * nn + zg * h0v;
        }
    }
}

// ---- logits = h @ W_out + b_out ------------------------------------------
__global__ __launch_bounds__(256) void logits_kernel(
        const float* __restrict__ H, const float* __restrict__ Wout,
        const float* __restrict__ bout, float* __restrict__ outL){
    __shared__ float Hl[16 * 260];
    __shared__ float Wl[16 * 260];
    int tid = threadIdx.x;
    int m0 = blockIdx.x * 16;
    #pragma unroll
    for (int i = 0; i < 4; ++i){
        int ci = tid + i * 256;
        int row = ci >> 6;
        int c4 = (ci & 63) << 2;
        int gr = m0 + row; if (gr >= N_DSTN) gr = N_DSTN - 1;
        float4 v = *reinterpret_cast<const float4*>(H + (size_t)gr * 256 + c4);
        float* dp = Hl + row * 260 + c4;
        dp[0] = v.x; dp[1] = v.y; dp[2] = v.z; dp[3] = v.w;
    }
    #pragma unroll
    for (int i = 0; i < 16; ++i){
        int ci = tid + i * 256;
        int c = ci >> 4, j = ci & 15;
        Wl[j * 260 + c] = Wout[c * 16 + j];
    }
    __syncthreads();
    int row = tid >> 4, j = tid & 15;
    const float* hr = Hl + row * 260;
    const float* wr = Wl + j * 260;
    float acc = bout[j];
    #pragma unroll
    for (int c = 0; c < 256; c += 4){
        float4 hv = *reinterpret_cast<const float4*>(hr + c);
        float4 wv = *reinterpret_cast<const float4*>(wr + c);
        acc = fmaf(hv.x, wv.x, fmaf(hv.y, wv.y, fmaf(hv.z, wv.z, fmaf(hv.w, wv.w, acc))));
    }
    int m = m0 + row;
    if (m < N_DSTN) outL[m * 16 + j] = acc;
}

extern "C" void kernel_launch(void* const* d_in, const int* in_sizes, int n_in,
                              void* d_out, int out_size, void* d_ws, size_t ws_size,
                              hipStream_t stream){
    const float* feat_gt = (const float*)d_in[0];
    const float* feat_ag = (const float*)d_in[1];
    const float* h0      = (const float*)d_in[2];
    const int*   e_src   = (const int*)d_in[3];
    const int*   e_dst   = (const int*)d_in[4];
    const float* W_src   = (const float*)d_in[5];
    const float* b_src   = (const float*)d_in[6];
    const float* W_dst   = (const float*)d_in[7];
    const float* b_dst   = (const float*)d_in[8];
    const float* attn    = (const float*)d_in[9];
    const float* W_res   = (const float*)d_in[10];
    const float* b_res   = (const float*)d_in[11];
    const float* W_ih    = (const float*)d_in[12];
    const float* W_hh    = (const float*)d_in[13];
    const float* b_ih    = (const float*)d_in[14];
    const float* b_hh    = (const float*)d_in[15];
    const float* W_out   = (const float*)d_in[16];
    const float* b_out   = (const float*)d_in[17];

    float* outL = (float*)d_out;
    float* outH = outL + (size_t)N_DSTN * 16;

    char* ws = (char*)d_ws;
    size_t off = 0;
    auto alloc = [&](size_t bytes) -> void* {
        void* p = ws + off; off = (off + bytes + 255) & ~(size_t)255; return p;
    };
    unsigned short* fs   = (unsigned short*)alloc((size_t)N_SRCN * 256 * 2);
    unsigned short* fd   = (unsigned short*)alloc((size_t)N_DSTN * 256 * 2);
    unsigned short* res  = (unsigned short*)alloc((size_t)N_DSTN * 256 * 2);
    unsigned short* xb   = (unsigned short*)alloc((size_t)N_DSTN * 256 * 2);
    unsigned short* Wt2  = (unsigned short*)alloc(49152 * 2);
    unsigned short* Wf   = (unsigned short*)alloc(393216 * 2);
    int* deg    = (int*)alloc(N_DSTN * 4);
    int* ptr    = (int*)alloc(N_DSTN * 4);
    int* cursor = (int*)alloc(N_DSTN * 4);
    int* csr    = (int*)alloc((size_t)NE * 4);
    int* bsum   = (int*)alloc(256 * 4);
    int* boff   = (int*)alloc(256 * 4);

    hipMemsetAsync(deg, 0, N_DSTN * 4, stream);
    pack_kernel<<<1728, 256, 0, stream>>>(W_src, W_dst, W_res, W_ih, W_hh, Wt2, Wf);

    proj_kernel<<<dim3(4, 782, 3), 256, 0, stream>>>(feat_gt, feat_ag, Wt2,
                                                     b_src, b_dst, b_res, fs, fd, res);

    degree_kernel<<<3125, 256, 0, stream>>>(e_dst, deg);
    scan1_kernel<<<196, 256, 0, stream>>>(deg, bsum);
    scan2_kernel<<<1, 256, 0, stream>>>(bsum, boff);
    scan3_kernel<<<196, 256, 0, stream>>>(deg, boff, ptr, cursor);
    scatter_kernel<<<3125, 256, 0, stream>>>(e_src, e_dst, cursor, csr);
    aggregate_kernel<<<12500, 256, 0, stream>>>(fs, fd, res, attn, ptr, deg, csr, xb);

    gru_kernel<<<1563, 512, 0, stream>>>(xb, h0, Wf, b_ih, b_hh, outH);
    logits_kernel<<<3125, 256, 0, stream>>>(outH, W_out, b_out, outL);
}

// Round 10
// 445.499 us; speedup vs baseline: 1.1370x; 1.0008x over previous
//
#include <hip/hip_runtime.h>
#include <stdint.h>

#define N_SRCN 50000
#define N_DSTN 50000
#define NE     800000
#define HIDN   256
#define NEG    0.2f

typedef __attribute__((ext_vector_type(8)))  short short8;
typedef __attribute__((ext_vector_type(16))) float float16v;

__device__ __forceinline__ float bf2f(unsigned short u){
    union { unsigned u32; float f; } c; c.u32 = ((unsigned)u) << 16; return c.f;
}
__device__ __forceinline__ unsigned short f2bf(float f){
    union { float f; unsigned u; } c; c.f = f;
    unsigned r = c.u + 0x7fffu + ((c.u >> 16) & 1u);
    return (unsigned short)(r >> 16);
}
__device__ __forceinline__ float4 ld4b(const unsigned short* p){
    uint2 u = *reinterpret_cast<const uint2*>(p);
    float4 r;
    r.x = bf2f((unsigned short)(u.x & 0xffff));
    r.y = bf2f((unsigned short)(u.x >> 16));
    r.z = bf2f((unsigned short)(u.y & 0xffff));
    r.w = bf2f((unsigned short)(u.y >> 16));
    return r;
}
__device__ __forceinline__ void unpack8(uint4 u, float* f){
    f[0] = bf2f((unsigned short)(u.x & 0xffff)); f[1] = bf2f((unsigned short)(u.x >> 16));
    f[2] = bf2f((unsigned short)(u.y & 0xffff)); f[3] = bf2f((unsigned short)(u.y >> 16));
    f[4] = bf2f((unsigned short)(u.z & 0xffff)); f[5] = bf2f((unsigned short)(u.z >> 16));
    f[6] = bf2f((unsigned short)(u.w & 0xffff)); f[7] = bf2f((unsigned short)(u.w >> 16));
}
// async 16B global -> LDS (wave-uniform LDS base + lane*16 dest; PER-LANE src)
__device__ __forceinline__ void gload_lds16(const unsigned short* g, unsigned short* l){
    __builtin_amdgcn_global_load_lds(
        (const __attribute__((address_space(1))) void*)g,
        (__attribute__((address_space(3))) void*)l,
        16, 0, 0);
}

// ---- pack weights, input-indexed (coalesced reads, scattered 2B writes) ----
// Wt2: [which(3)][cb(8)][kk(4)][lane(64)][8]   (49152)
// Wf : [cb(8)][kk(32)][gate(3)][lane(64)][8]   (393216), K=512 = [Wih|Whh]
//      gates adjacent per (cb,kk): one base addr + imm offsets 0/1024/2048 B
__global__ void pack_kernel(const float* __restrict__ Wsrc, const float* __restrict__ Wdst,
                            const float* __restrict__ Wres, const float* __restrict__ Wih,
                            const float* __restrict__ Whh,
                            unsigned short* __restrict__ Wt2,
                            unsigned short* __restrict__ Wf){
    int i = blockIdx.x * 256 + threadIdx.x;
    if (i < 49152){
        int which = i >> 14, j = i & 16383;          // j = k*256 + c
        int k = j >> 8, c = j & 255;
        const float* W = (which == 0) ? Wsrc : (which == 1 ? Wdst : Wres);
        float v = W[j];
        int off = which * 16384 + (c >> 5) * 2048 + (k >> 4) * 512
                + (((k >> 3) & 1) * 32 + (c & 31)) * 8 + (k & 7);
        Wt2[off] = f2bf(v);
    } else if (i < 49152 + 196608){
        int o = i - 49152;                            // Wih flat: (g*256+c)*256+k
        int row = o >> 8, k = o & 255;
        int g = row >> 8, c = row & 255;
        float v = Wih[o];
        int off = (c >> 5) * 49152 + (k >> 4) * 1536 + g * 512
                + (((k >> 3) & 1) * 32 + (c & 31)) * 8 + (k & 7);
        Wf[off] = f2bf(v);
    } else if (i < 49152 + 393216){
        int o = i - 49152 - 196608;                   // Whh
        int row = o >> 8, k = o & 255;
        int g = row >> 8, c = row & 255;
        float v = Whh[o];
        int off = (c >> 5) * 49152 + (16 + (k >> 4)) * 1536 + g * 512
                + (((k >> 3) & 1) * 32 + (c & 31)) * 8 + (k & 7);
        Wf[off] = f2bf(v);
    }
}

// ---- fused projection GEMM (K=64), z selects {src, dst, res} --------------
// v2: col-block loop folded in-kernel: A staged+converted ONCE (was 4x),
// 2346 blocks instead of 9384 (launch overhead / 4).
__global__ __launch_bounds__(256) void proj_kernel(
        const float* __restrict__ Agt, const float* __restrict__ Aag,
        const unsigned short* __restrict__ Wt2,
        const float* __restrict__ bsrc, const float* __restrict__ bdst,
        const float* __restrict__ bres,
        unsigned short* __restrict__ fs, unsigned short* __restrict__ fd,
        unsigned short* __restrict__ resb){
    __shared__ unsigned short As[64 * 72];
    __shared__ unsigned short Cs[64 * 72];
    int z = blockIdx.y;
    const float* A = (z == 0) ? Agt : Aag;
    const float* bias = (z == 0) ? bsrc : (z == 1 ? bdst : bres);
    unsigned short* out = (z == 0) ? fs : (z == 1 ? fd : resb);
    const unsigned short* Wb = Wt2 + z * 16384;
    int tid = threadIdx.x;
    int m0 = blockIdx.x * 64;
    #pragma unroll
    for (int i = 0; i < 4; ++i){
        int ci = tid + i * 256;
        int row = ci >> 4;
        int k4 = (ci & 15) << 2;
        int gr = m0 + row; if (gr >= N_SRCN) gr = N_SRCN - 1;
        float4 v = *reinterpret_cast<const float4*>(A + (size_t)gr * 64 + k4);
        unsigned short* dp = As + row * 72 + k4;
        dp[0] = f2bf(v.x); dp[1] = f2bf(v.y); dp[2] = f2bf(v.z); dp[3] = f2bf(v.w);
    }
    __syncthreads();
    int lane = tid & 63, w = tid >> 6;
    int l31 = lane & 31, half = lane >> 5;
    int msub = (w & 1) * 32;
    const unsigned short* ap = As + (msub + l31) * 72 + half * 8;
    int srow = tid >> 2, chunk = tid & 3;
    int gr2 = m0 + srow;
    for (int xb = 0; xb < 4; ++xb){
        if (xb) __syncthreads();                 // Cs reuse fence
        int cbw = xb * 2 + (w >> 1);
        const unsigned short* bb = Wb + cbw * 2048 + lane * 8;
        float16v acc = {0,0,0,0,0,0,0,0,0,0,0,0,0,0,0,0};
        #pragma unroll
        for (int ks = 0; ks < 4; ++ks){
            short8 a = *reinterpret_cast<const short8*>(ap + ks * 16);
            short8 b = *reinterpret_cast<const short8*>(bb + ks * 512);
            acc = __builtin_amdgcn_mfma_f32_32x32x16_bf16(a, b, acc, 0, 0, 0);
        }
        float bv = bias[cbw * 32 + l31];
        int ccol = (w >> 1) * 32 + l31;
        #pragma unroll
        for (int r = 0; r < 16; ++r){
            int row = (r & 3) + 8 * (r >> 2) + 4 * half + msub;
            Cs[row * 72 + ccol] = f2bf(acc[r] + bv);
        }
        __syncthreads();
        if (gr2 < N_SRCN){
            const uint4* sp = reinterpret_cast<const uint4*>(Cs + srow * 72 + chunk * 16);
            uint4* gp = reinterpret_cast<uint4*>(out + (size_t)gr2 * 256 + xb * 64 + chunk * 16);
            gp[0] = sp[0];
            gp[1] = sp[1];
        }
    }
}

// ---- edge CSR build -------------------------------------------------------
__global__ void degree_kernel(const int* __restrict__ dst, int* __restrict__ deg){
    int i = blockIdx.x * 256 + threadIdx.x;
    if (i < NE) atomicAdd(&deg[dst[i]], 1);
}

__global__ void scan1_kernel(const int* __restrict__ deg, int* __restrict__ bsum){
    __shared__ int s[256];
    int tid = threadIdx.x;
    int i = blockIdx.x * 256 + tid;
    s[tid] = (i < N_DSTN) ? deg[i] : 0;
    __syncthreads();
    #pragma unroll
    for (int off = 128; off; off >>= 1){
        if (tid < off) s[tid] += s[tid + off];
        __syncthreads();
    }
    if (tid == 0) bsum[blockIdx.x] = s[0];
}

__global__ void scan2_kernel(const int* __restrict__ bsum, int* __restrict__ boff){
    __shared__ int s[256];
    int tid = threadIdx.x;
    int v = (tid < 196) ? bsum[tid] : 0;
    s[tid] = v;
    __syncthreads();
    #pragma unroll
    for (int off = 1; off < 256; off <<= 1){
        int t = (tid >= off) ? s[tid - off] : 0;
        __syncthreads();
        s[tid] += t;
        __syncthreads();
    }
    if (tid < 196) boff[tid] = s[tid] - v;
}

__global__ void scan3_kernel(const int* __restrict__ deg, const int* __restrict__ boff,
                             int* __restrict__ ptr, int* __restrict__ cursor){
    __shared__ int s[256];
    int tid = threadIdx.x;
    int i = blockIdx.x * 256 + tid;
    int v = (i < N_DSTN) ? deg[i] : 0;
    s[tid] = v;
    __syncthreads();
    #pragma unroll
    for (int off = 1; off < 256; off <<= 1){
        int t = (tid >= off) ? s[tid - off] : 0;
        __syncthreads();
        s[tid] += t;
        __syncthreads();
    }
    int ex = s[tid] - v + boff[blockIdx.x];
    if (i < N_DSTN){ ptr[i] = ex; cursor[i] = ex; }
}

__global__ void scatter_kernel(const int* __restrict__ src, const int* __restrict__ dst,
                               int* __restrict__ cursor, int* __restrict__ csr){
    int i = blockIdx.x * 256 + threadIdx.x;
    if (i < NE){
        int d = dst[i];
        int pos = atomicAdd(&cursor[d], 1);
        csr[pos] = src[i];
    }
}

// ---- aggregate v3: 2 edge-slots x 4-deep prefetch (8 edges in flight) -----
// v2 (instruction-halving) was NULL -> not VALU-bound. v3 tests the latency
// hypothesis: 4 row-pairs prefetched ahead per wave (4 uint4 in flight) +
// 512-thread blocks (8 d/block) for more resident waves. If the gather
// chain was the cost, Little's law says this is the fix.
__global__ __launch_bounds__(512) void aggregate_kernel(
        const unsigned short* __restrict__ fs, const unsigned short* __restrict__ fd,
        const unsigned short* __restrict__ res, const float* __restrict__ attn,
        const int* __restrict__ ptr, const int* __restrict__ deg,
        const int* __restrict__ csr, unsigned short* __restrict__ x){
    int wv = threadIdx.x >> 6;
    int d = blockIdx.x * 8 + wv;
    if (d >= N_DSTN) return;
    int lane = threadIdx.x & 63;
    int s = lane >> 5;                    // edge slot 0/1
    int sl = lane & 31;                   // sub-lane: cols [sl*8, sl*8+8)
    int c8 = sl * 8;
    float fdv[8];
    unpack8(*reinterpret_cast<const uint4*>(fd + (size_t)d * 256 + c8), fdv);
    const float* atp = attn + (sl >> 3) * 64 + (sl & 7) * 8;
    float4 at0 = *reinterpret_cast<const float4*>(atp);
    float4 at1 = *reinterpret_cast<const float4*>(atp + 4);
    float at[8] = {at0.x, at0.y, at0.z, at0.w, at1.x, at1.y, at1.z, at1.w};
    int p = ptr[d], dg = deg[d];
    float lsum = 0.f;
    float acc[8] = {0.f, 0.f, 0.f, 0.f, 0.f, 0.f, 0.f, 0.f};
    for (int base = 0; base < dg; base += 64){
        int cnt = min(64, dg - base);
        int sreg = (lane < cnt) ? csr[p + base + lane] : 0;
#define GROW(IDX) (*reinterpret_cast<const uint4*>( \
            fs + (size_t)__shfl(sreg, (IDX) & 63) * 256 + c8))
        uint4 b0 = GROW(0 + s);
        uint4 b1 = GROW(2 + s);
        uint4 b2 = GROW(4 + s);
        uint4 b3 = GROW(6 + s);
        for (int j = 0; j < cnt; j += 8){
            uint4 n0 = GROW(j + 8 + s);
            uint4 n1 = GROW(j + 10 + s);
            uint4 n2 = GROW(j + 12 + s);
            uint4 n3 = GROW(j + 14 + s);
#define PROC(BV, IDX) { \
            float b[8]; unpack8(BV, b); \
            float part = 0.f; \
            _Pragma("unroll") \
            for (int i = 0; i < 8; ++i){ \
                float e = b[i] + fdv[i]; \
                e = (e > 0.f) ? e : NEG * e; \
                part = fmaf(e, at[i], part); \
            } \
            part += __shfl_xor(part, 1); \
            part += __shfl_xor(part, 2); \
            part += __shfl_xor(part, 4); \
            float wgt = ((IDX) < cnt) ? __expf(part) : 0.f; \
            lsum += wgt; \
            _Pragma("unroll") \
            for (int i = 0; i < 8; ++i) acc[i] = fmaf(wgt, b[i], acc[i]); }
            PROC(b0, j + 0 + s) PROC(b1, j + 2 + s)
            PROC(b2, j + 4 + s) PROC(b3, j + 6 + s)
#undef PROC
            b0 = n0; b1 = n1; b2 = n2; b3 = n3;
        }
#undef GROW
    }
    // combine the two edge slots (partner lane has same cols, same head)
    lsum += __shfl_xor(lsum, 32);
    #pragma unroll
    for (int i = 0; i < 8; ++i) acc[i] += __shfl_xor(acc[i], 32);
    float inv = (lsum > 0.f) ? 1.f / lsum : 0.f;
    float rv[8];
    unpack8(*reinterpret_cast<const uint4*>(res + (size_t)d * 256 + c8), rv);
    unsigned short ob[8];
    #pragma unroll
    for (int i = 0; i < 8; ++i)
        ob[i] = f2bf(fmaxf(fmaf(acc[i], inv, rv[i]), 0.f));
    if (s == 0){
        uint4 o;
        o.x = (unsigned)ob[0] | ((unsigned)ob[1] << 16);
        o.y = (unsigned)ob[2] | ((unsigned)ob[3] << 16);
        o.z = (unsigned)ob[4] | ((unsigned)ob[5] << 16);
        o.w = (unsigned)ob[6] | ((unsigned)ob[7] << 16);
        *reinterpret_cast<uint4*>(x + (size_t)d * 256 + c8) = o;
    }
}

// ---- GRU v11 (best measured: 115us): barrier-free K-loop; B global->reg ---
__global__ __launch_bounds__(512, 4) void gru_kernel(
        const unsigned short* __restrict__ Xb,
        const float* __restrict__ H0, const unsigned short* __restrict__ Wf,
        const float* __restrict__ bih, const float* __restrict__ bhh,
        float* __restrict__ outH){
    __shared__ unsigned short As[2 * 32 * 256];  // 32KB: [X 32x256][H 32x256]
    int tid = threadIdx.x;
    int m0 = blockIdx.x << 5;                    // 32 rows/block
    int w = tid >> 6, lane = tid & 63;

    // ---- prologue A: X region via async gload (swizzled SOURCE, linear dest)
    #pragma unroll
    for (int i = 0; i < 2; ++i){
        int g = w + i * 8;                       // 0..15, rows {2g, 2g+1}
        int row = 2 * g + (lane >> 5);
        int gr = m0 + row; if (gr >= N_DSTN) gr = N_DSTN - 1;
        int j = lane & 31;
        const unsigned short* src = Xb + (size_t)gr * 256 + ((j ^ (row & 15)) << 3);
        gload_lds16(src, As + g * 512);
    }
    // ---- prologue A: H region reg-staged f32->bf16 (once per element)
    {
        int hrow = tid >> 4, hseg = tid & 15;    // 32 rows x 16 segs of 16 f32
        int hgr = m0 + hrow; if (hgr >= N_DSTN) hgr = N_DSTN - 1;
        const float* hp = H0 + (size_t)hgr * 256 + hseg * 16;
        float4 f0 = *reinterpret_cast<const float4*>(hp);
        float4 f1 = *reinterpret_cast<const float4*>(hp + 4);
        float4 f2 = *reinterpret_cast<const float4*>(hp + 8);
        float4 f3 = *reinterpret_cast<const float4*>(hp + 12);
        int rl = hrow & 15;
        int c0 = hseg * 2;
        uint4 o;
        o.x = (unsigned)f2bf(f0.x) | ((unsigned)f2bf(f0.y) << 16);
        o.y = (unsigned)f2bf(f0.z) | ((unsigned)f2bf(f0.w) << 16);
        o.z = (unsigned)f2bf(f1.x) | ((unsigned)f2bf(f1.y) << 16);
        o.w = (unsigned)f2bf(f1.z) | ((unsigned)f2bf(f1.w) << 16);
        *reinterpret_cast<uint4*>(As + 8192 + hrow * 256 + ((c0 ^ rl) << 3)) = o;
        o.x = (unsigned)f2bf(f2.x) | ((unsigned)f2bf(f2.y) << 16);
        o.y = (unsigned)f2bf(f2.z) | ((unsigned)f2bf(f2.w) << 16);
        o.z = (unsigned)f2bf(f3.x) | ((unsigned)f2bf(f3.y) << 16);
        o.w = (unsigned)f2bf(f3.z) | ((unsigned)f2bf(f3.w) << 16);
        *reinterpret_cast<uint4*>(As + 8192 + hrow * 256 + (((c0 + 1) ^ rl) << 3)) = o;
    }
    asm volatile("s_waitcnt vmcnt(0) lgkmcnt(0)" ::: "memory");
    __syncthreads();                             // the ONLY barrier

    int l31 = lane & 31, half = lane >> 5;
    int ct = w;                                  // 8 col-tiles of 32
    int rl = l31 & 15;
    const unsigned short* bb = Wf + ct * 49152 + lane * 8;   // gate-adjacent
    float16v zv = {0,0,0,0,0,0,0,0,0,0,0,0,0,0,0,0};
    float16v ar = zv, az = zv, anx = zv, anh = zv;
    #pragma unroll
    for (int p = 0; p < 32; ++p){
        const unsigned short* bp = bb + p * 1536;
        short8 vr = *reinterpret_cast<const short8*>(bp);          // off 0
        short8 vz = *reinterpret_cast<const short8*>(bp + 512);    // off 1024B
        short8 vn = *reinterpret_cast<const short8*>(bp + 1024);   // off 2048B
        const unsigned short* ap_ = (p < 16) ? As : (As + 8192);
        int kl = p & 15;
        short8 a = *reinterpret_cast<const short8*>(
                       ap_ + l31 * 256 + (((kl * 2 + half) ^ rl) << 3));
        ar = __builtin_amdgcn_mfma_f32_32x32x16_bf16(a, vr, ar, 0, 0, 0);
        az = __builtin_amdgcn_mfma_f32_32x32x16_bf16(a, vz, az, 0, 0, 0);
        if (p < 16) anx = __builtin_amdgcn_mfma_f32_32x32x16_bf16(a, vn, anx, 0, 0, 0);
        else        anh = __builtin_amdgcn_mfma_f32_32x32x16_bf16(a, vn, anh, 0, 0, 0);
    }
    // fused GRU epilogue; H0 rows are L2-hot (read in prologue by this block)
    int cg = ct * 32 + l31;
    float rb = bih[cg] + bhh[cg];
    float zb = bih[256 + cg] + bhh[256 + cg];
    float bin = bih[512 + cg], bhn = bhh[512 + cg];
    #pragma unroll
    for (int r = 0; r < 16; ++r){
        int m = m0 + (r & 3) + 8 * (r >> 2) + 4 * half;
        if (m < N_DSTN){
            float h0v = H0[(size_t)m * 256 + cg];
            float rrg = 1.f / (1.f + __expf(-(ar[r] + rb)));
            float zg  = 1.f / (1.f + __expf(-(az[r] + zb)));
            float nx = anx[r] + bin + rrg * (anh[r] + bhn);
            float tm = __expf(-2.f * fabsf(nx));
            float nn = (1.f - tm) / (1.f + tm);
            nn = (nx >= 0.f) ? nn : -nn;
            outH[(size_t)m * 256 + cg] = (1.f - zg) * nn + zg * h0v;
        }
    }
}

// ---- logits = h @ W_out + b_out ------------------------------------------
__global__ __launch_bounds__(256) void logits_kernel(
        const float* __restrict__ H, const float* __restrict__ Wout,
        const float* __restrict__ bout, float* __restrict__ outL){
    __shared__ float Hl[16 * 260];
    __shared__ float Wl[16 * 260];
    int tid = threadIdx.x;
    int m0 = blockIdx.x * 16;
    #pragma unroll
    for (int i = 0; i < 4; ++i){
        int ci = tid + i * 256;
        int row = ci >> 6;
        int c4 = (ci & 63) << 2;
        int gr = m0 + row; if (gr >= N_DSTN) gr = N_DSTN - 1;
        float4 v = *reinterpret_cast<const float4*>(H + (size_t)gr * 256 + c4);
        float* dp = Hl + row * 260 + c4;
        dp[0] = v.x; dp[1] = v.y; dp[2] = v.z; dp[3] = v.w;
    }
    #pragma unroll
    for (int i = 0; i < 16; ++i){
        int ci = tid + i * 256;
        int c = ci >> 4, j = ci & 15;
        Wl[j * 260 + c] = Wout[c * 16 + j];
    }
    __syncthreads();
    int row = tid >> 4, j = tid & 15;
    const float* hr = Hl + row * 260;
    const float* wr = Wl + j * 260;
    float acc = bout[j];
    #pragma unroll
    for (int c = 0; c < 256; c += 4){
        float4 hv = *reinterpret_cast<const float4*>(hr + c);
        float4 wv = *reinterpret_cast<const float4*>(wr + c);
        acc = fmaf(hv.x, wv.x, fmaf(hv.y, wv.y, fmaf(hv.z, wv.z, fmaf(hv.w, wv.w, acc))));
    }
    int m = m0 + row;
    if (m < N_DSTN) outL[m * 16 + j] = acc;
}

extern "C" void kernel_launch(void* const* d_in, const int* in_sizes, int n_in,
                              void* d_out, int out_size, void* d_ws, size_t ws_size,
                              hipStream_t stream){
    const float* feat_gt = (const float*)d_in[0];
    const float* feat_ag = (const float*)d_in[1];
    const float* h0      = (const float*)d_in[2];
    const int*   e_src   = (const int*)d_in[3];
    const int*   e_dst   = (const int*)d_in[4];
    const float* W_src   = (const float*)d_in[5];
    const float* b_src   = (const float*)d_in[6];
    const float* W_dst   = (const float*)d_in[7];
    const float* b_dst   = (const float*)d_in[8];
    const float* attn    = (const float*)d_in[9];
    const float* W_res   = (const float*)d_in[10];
    const float* b_res   = (const float*)d_in[11];
    const float* W_ih    = (const float*)d_in[12];
    const float* W_hh    = (const float*)d_in[13];
    const float* b_ih    = (const float*)d_in[14];
    const float* b_hh    = (const float*)d_in[15];
    const float* W_out   = (const float*)d_in[16];
    const float* b_out   = (const float*)d_in[17];

    float* outL = (float*)d_out;
    float* outH = outL + (size_t)N_DSTN * 16;

    char* ws = (char*)d_ws;
    size_t off = 0;
    auto alloc = [&](size_t bytes) -> void* {
        void* p = ws + off; off = (off + bytes + 255) & ~(size_t)255; return p;
    };
    unsigned short* fs   = (unsigned short*)alloc((size_t)N_SRCN * 256 * 2);
    unsigned short* fd   = (unsigned short*)alloc((size_t)N_DSTN * 256 * 2);
    unsigned short* res  = (unsigned short*)alloc((size_t)N_DSTN * 256 * 2);
    unsigned short* xb   = (unsigned short*)alloc((size_t)N_DSTN * 256 * 2);
    unsigned short* Wt2  = (unsigned short*)alloc(49152 * 2);
    unsigned short* Wf   = (unsigned short*)alloc(393216 * 2);
    int* deg    = (int*)alloc(N_DSTN * 4);
    int* ptr    = (int*)alloc(N_DSTN * 4);
    int* cursor = (int*)alloc(N_DSTN * 4);
    int* csr    = (int*)alloc((size_t)NE * 4);
    int* bsum   = (int*)alloc(256 * 4);
    int* boff   = (int*)alloc(256 * 4);

    hipMemsetAsync(deg, 0, N_DSTN * 4, stream);
    pack_kernel<<<1728, 256, 0, stream>>>(W_src, W_dst, W_res, W_ih, W_hh, Wt2, Wf);

    proj_kernel<<<dim3(782, 3), 256, 0, stream>>>(feat_gt, feat_ag, Wt2,
                                                  b_src, b_dst, b_res, fs, fd, res);

    degree_kernel<<<3125, 256, 0, stream>>>(e_dst, deg);
    scan1_kernel<<<196, 256, 0, stream>>>(deg, bsum);
    scan2_kernel<<<1, 256, 0, stream>>>(bsum, boff);
    scan3_kernel<<<196, 256, 0, stream>>>(deg, boff, ptr, cursor);
    scatter_kernel<<<3125, 256, 0, stream>>>(e_src, e_dst, cursor, csr);
    aggregate_kernel<<<6250, 512, 0, stream>>>(fs, fd, res, attn, ptr, deg, csr, xb);

    gru_kernel<<<1563, 512, 0, stream>>>(xb, h0, Wf, b_ih, b_hh, outH);
    logits_kernel<<<3125, 256, 0, stream>>>(outH, W_out, b_out, outL);
}